// Round 11
// baseline (836.883 us; speedup 1.0000x reference)
//
#include <hip/hip_runtime.h>
#include <hip/hip_bf16.h>
#include <stdint.h>

#define N_NODES 100000
#define N_EDGES 1600000
#define D_FEAT 32
#define CUT_K 320000        // int(N_EDGES * 0.2)
#define COSKEY_NB 4096      // coskey grid: enough blocks for full occupancy
#define HC_NB 1000          // histc blocks; E = HC_NB * HC_SLICE exactly
#define HC_SLICE 1600
#define SCAN_NB ((N_NODES + 255) / 256)   // 391
#define BKT_SHIFT 6
#define BKT_NODES 64
#define NBKT ((N_NODES + BKT_NODES - 1) / BKT_NODES)   // 1563
#define WIN_CAP 4608        // LDS window (mean bucket ~1024 edges, 4.5x margin)

struct SelState { unsigned long long prefix; unsigned int k; };

__global__ void deg_kernel(const int* __restrict__ dst, int* __restrict__ deg, int E) {
    int e = blockIdx.x * blockDim.x + threadIdx.x;
    if (e < E) atomicAdd(&deg[dst[e]], 1);
}

__global__ void norm_kernel(const int* __restrict__ deg, float* __restrict__ nrm, int N) {
    int i = blockIdx.x * blockDim.x + threadIdx.x;
    if (i < N) nrm[i] = 1.0f / sqrtf(fmaxf((float)deg[i], 1.0f));
}

// ---- parallel exclusive scan of deg (3 kernels) ----
__global__ void blocksum_kernel(const int* __restrict__ deg, int* __restrict__ bsum, int N) {
    int i = blockIdx.x * 256 + threadIdx.x;
    int v = (i < N) ? deg[i] : 0;
#pragma unroll
    for (int off = 32; off > 0; off >>= 1) v += __shfl_down(v, off, 64);
    __shared__ int ws4[4];
    if ((threadIdx.x & 63) == 0) ws4[threadIdx.x >> 6] = v;
    __syncthreads();
    if (threadIdx.x == 0) bsum[blockIdx.x] = ws4[0] + ws4[1] + ws4[2] + ws4[3];
}

__global__ void scanpartial_kernel(const int* __restrict__ bsum, int* __restrict__ boff, int B) {
    __shared__ int buf[512];
    int t = threadIdx.x;
    int v = (t < B) ? bsum[t] : 0;
    buf[t] = v;
    __syncthreads();
    for (int off = 1; off < 512; off <<= 1) {
        int u = (t >= off) ? buf[t - off] : 0;
        __syncthreads();
        buf[t] += u;
        __syncthreads();
    }
    if (t < B) boff[t] = buf[t] - v;   // exclusive
}

__global__ void writeoffs_kernel(const int* __restrict__ deg, const int* __restrict__ boff,
                                 int* __restrict__ offs, int N) {
    __shared__ int buf[256];
    int t = threadIdx.x;
    int i = blockIdx.x * 256 + t;
    int v = (i < N) ? deg[i] : 0;
    buf[t] = v;
    __syncthreads();
    for (int off = 1; off < 256; off <<= 1) {
        int u = (t >= off) ? buf[t - off] : 0;
        __syncthreads();
        buf[t] += u;
        __syncthreads();
    }
    int ex = buf[t] - v + boff[blockIdx.x];
    if (i < N) offs[i] = ex;
    if (i == N - 1) offs[N] = ex + v;   // == E
}

// bucket cursors: bucket b owns slot range [offs[b*64], offs[min((b+1)*64,N)))
__global__ void bcur_init_kernel(const int* __restrict__ offs, int* __restrict__ bcur, int nb) {
    int b = blockIdx.x * blockDim.x + threadIdx.x;
    if (b < nb) bcur[b] = offs[b * BKT_NODES];
}

// coarse scatter: append eid into its dst-bucket region. Active write frontier is
// only NBKT lines (~100 KB, cache-resident) -> each 64B line absorbs ~16 appends.
__global__ void fill_bkt_kernel(const int* __restrict__ dst, int* __restrict__ bcur,
                                int* __restrict__ csr_eid, int E) {
    int e = blockIdx.x * blockDim.x + threadIdx.x;
    if (e >= E) return;
    int pos = atomicAdd(&bcur[dst[e] >> BKT_SHIFT], 1);
    csr_eid[pos] = e;
}

// per-bucket: stage window in LDS, scatter to exact per-node slots (LDS cursors),
// insertion-sort each node segment by eid (canonical -> bitwise-deterministic
// pipeline), write back dense. Block-uniform fallback for window overflow.
__global__ void binsort_kernel(const int* __restrict__ dst, const int* __restrict__ offs,
                               int* __restrict__ csr_eid, int* __restrict__ scratch, int N) {
    __shared__ int win[WIN_CAP];
    __shared__ int scur[BKT_NODES];
    __shared__ int sstart[BKT_NODES + 1];
    int b = blockIdx.x;
    int lo = b * BKT_NODES;
    int hi = min(lo + BKT_NODES, N);
    int nn = hi - lo;
    int t = threadIdx.x;
    int base = offs[lo];
    int n = offs[hi] - base;
    if (t <= nn) sstart[t] = offs[lo + t] - base;
    if (t < nn) scur[t] = offs[lo + t] - base;
    __syncthreads();
    if (n <= WIN_CAP) {
        for (int i = t; i < n; i += 256) {
            int eid = csr_eid[base + i];
            int pos = atomicAdd(&scur[dst[eid] - lo], 1);
            win[pos] = eid;
        }
        __syncthreads();
        if (t < nn) {
            int s0 = sstart[t], s1 = sstart[t + 1];
            for (int i = s0 + 1; i < s1; ++i) {
                int key = win[i]; int j = i - 1;
                while (j >= s0 && win[j] > key) { win[j + 1] = win[j]; --j; }
                win[j + 1] = key;
            }
        }
        __syncthreads();
        for (int i = t; i < n; i += 256) csr_eid[base + i] = win[i];
    } else {   // overflow fallback (practically unreachable; correctness-only)
        for (int i = t; i < n; i += 256) scratch[base + i] = csr_eid[base + i];
        __syncthreads();
        for (int i = t; i < n; i += 256) {
            int eid = scratch[base + i];
            int pos = atomicAdd(&scur[dst[eid] - lo], 1);
            csr_eid[base + pos] = eid;
        }
        __syncthreads();
        if (t < nn) {
            int s0 = base + sstart[t], s1 = base + sstart[t + 1];
            for (int i = s0 + 1; i < s1; ++i) {
                int key = csr_eid[i]; int j = i - 1;
                while (j >= s0 && csr_eid[j] > key) { csr_eid[j + 1] = csr_eid[j]; --j; }
                csr_eid[j + 1] = key;
            }
        }
    }
}

// once per call: materialize csr_src / csr_dst with coalesced writes.
__global__ void expand_kernel(const int* __restrict__ src, const int* __restrict__ offs,
                              const int* __restrict__ csr_eid,
                              int* __restrict__ csr_src, int* __restrict__ csr_dst, int N) {
    int g = blockIdx.x * 8 + (threadIdx.x >> 5);
    int j = threadIdx.x & 31;
    if (g >= N) return;
    int lo = offs[g], hi = offs[g + 1];
    for (int p = lo + j; p < hi; p += 32) {
        csr_dst[p] = g;
        csr_src[p] = src[csr_eid[p]];
    }
}

// nh = h / max(||h||,1e-12)  AND  hs = h * nrm  (fused); thread 0 also resets st
__global__ void rownorm_kernel(const float* __restrict__ h, float* __restrict__ nh,
                               float* __restrict__ hs, const float* __restrict__ nrm,
                               SelState* __restrict__ st, int N) {
    int i = blockIdx.x * blockDim.x + threadIdx.x;
    if (i == 0) { st->prefix = 0ull; st->k = CUT_K; }
    if (i >= N) return;
    const float4* hp = (const float4*)(h + (size_t)i * D_FEAT);
    float4 v[8];
    float ss = 0.f;
#pragma unroll
    for (int q = 0; q < 8; ++q) {
        v[q] = hp[q];
        ss += v[q].x * v[q].x + v[q].y * v[q].y + v[q].z * v[q].z + v[q].w * v[q].w;
    }
    float inv = 1.0f / fmaxf(sqrtf(ss), 1e-12f);
    float sc = nrm[i];
    float4* op = (float4*)(nh + (size_t)i * D_FEAT);
    float4* sp = (float4*)(hs + (size_t)i * D_FEAT);
#pragma unroll
    for (int q = 0; q < 8; ++q) {
        float4 ov = v[q];
        float4 sv = v[q];
        ov.x *= inv; ov.y *= inv; ov.z *= inv; ov.w *= inv;
        sv.x *= sc;  sv.y *= sc;  sv.z *= sc;  sv.w *= sc;
        op[q] = ov;
        sp[q] = sv;
    }
}

// keys[p] = (sortable(cos_p) << 32) | orig_eid; fused pass-0 histogram (top 8 bits)
__global__ void coskey_kernel(const float* __restrict__ nh, const int* __restrict__ csr_src,
                              const int* __restrict__ csr_dst, const int* __restrict__ csr_eid,
                              unsigned long long* __restrict__ keys,
                              unsigned int* __restrict__ ghist, int E) {
    __shared__ unsigned int lh[4][256];
    int t = threadIdx.x;
#pragma unroll
    for (int w = 0; w < 4; ++w) lh[w][t] = 0u;
    __syncthreads();
    int wave = t >> 6;
    int stride = gridDim.x * blockDim.x;
    for (int p = blockIdx.x * blockDim.x + t; p < E; p += stride) {
        const float4* a = (const float4*)(nh + (size_t)csr_src[p] * D_FEAT);
        const float4* b = (const float4*)(nh + (size_t)csr_dst[p] * D_FEAT);
        float s = 0.f;
#pragma unroll
        for (int q = 0; q < 8; ++q) {
            float4 x = a[q], y = b[q];
            s += x.x * y.x + x.y * y.y + x.z * y.z + x.w * y.w;
        }
        unsigned int u = __float_as_uint(s);
        unsigned int so = (u & 0x80000000u) ? ~u : (u | 0x80000000u);
        unsigned long long key = ((unsigned long long)so << 32) | (unsigned int)csr_eid[p];
        keys[p] = key;
        atomicAdd(&lh[wave][(unsigned int)(key >> 56)], 1u);
    }
    __syncthreads();
    unsigned int tot = lh[0][t] + lh[1][t] + lh[2][t] + lh[3][t];
    if (tot) atomicAdd(&ghist[t], tot);
}

// compacting radix pass p (1..7), slice-deterministic
__global__ void histc_kernel(const unsigned long long* __restrict__ in,
                             const int* __restrict__ cnt_in,      // null => dense (pass 1)
                             unsigned long long* __restrict__ out,
                             int* __restrict__ cnt_out,
                             const SelState* __restrict__ st,
                             unsigned int* __restrict__ ghist, int pass) {
    __shared__ unsigned int lh[4][256];
    __shared__ unsigned int lcnt;
    int t = threadIdx.x, b = blockIdx.x;
#pragma unroll
    for (int w = 0; w < 4; ++w) lh[w][t] = 0u;
    if (t == 0) lcnt = 0u;
    __syncthreads();
    unsigned long long prefix = st->prefix;
    int n = cnt_in ? cnt_in[b] : HC_SLICE;
    const unsigned long long* sin = in + (size_t)b * HC_SLICE;
    unsigned long long* sout = out + (size_t)b * HC_SLICE;
    int wave = t >> 6;
    int fshift = 64 - 8 * pass;
    int dshift = 56 - 8 * pass;
    for (int i = t; i < n; i += 256) {
        unsigned long long key = sin[i];
        if ((key >> fshift) == prefix) {
            atomicAdd(&lh[wave][(unsigned int)((key >> dshift) & 0xFFull)], 1u);
            unsigned int slot = atomicAdd(&lcnt, 1u);   // LDS atomic, block-local
            sout[slot] = key;
        }
    }
    __syncthreads();
    if (t == 0) cnt_out[b] = (int)lcnt;
    unsigned int tot = lh[0][t] + lh[1][t] + lh[2][t] + lh[3][t];
    if (tot) atomicAdd(&ghist[t], tot);
}

// single block of 256: scan 256-bin global hist, pick digit at rank k, zero hist
__global__ void scan8_kernel(unsigned int* __restrict__ ghist, SelState* __restrict__ st) {
    __shared__ unsigned int buf[256];
    int t = threadIdx.x;
    unsigned int k = st->k;            // read before any write
    unsigned int s = ghist[t];
    buf[t] = s;
    __syncthreads();
    for (int off = 1; off < 256; off <<= 1) {
        unsigned int v = (t >= off) ? buf[t - off] : 0u;
        __syncthreads();
        buf[t] += v;
        __syncthreads();
    }
    unsigned int incl = buf[t];
    unsigned int excl = incl - s;
    if (excl < k && k <= incl) {       // exactly one thread wins
        st->prefix = (st->prefix << 8) | (unsigned long long)t;
        st->k = k - excl;
    }
    ghist[t] = 0u;                     // ready for next pass/hop
}

// pull aggregation: one 32-lane group per node walks its (eid-sorted) CSR segment.
__global__ void aggregate_csr_kernel(const float* __restrict__ hs, float* __restrict__ h_out,
                                     const int* __restrict__ offs, const int* __restrict__ csr_src,
                                     const unsigned long long* __restrict__ keys,
                                     const SelState* __restrict__ st,
                                     const float* __restrict__ nrm, int N) {
    unsigned long long kth = st->prefix;   // cut_k-th smallest composite key
    int g = blockIdx.x * 8 + (threadIdx.x >> 5);
    int j = threadIdx.x & 31;
    if (g >= N) return;
    int lo = offs[g], hi = offs[g + 1];
    float acc = 0.f;
    int p = lo;
    for (; p + 8 <= hi; p += 8) {
        unsigned long long kk[8];
        int ss[8];
#pragma unroll
        for (int u = 0; u < 8; ++u) { kk[u] = keys[p + u]; ss[u] = csr_src[p + u]; }
        float vv[8];
#pragma unroll
        for (int u = 0; u < 8; ++u) vv[u] = hs[(size_t)ss[u] * D_FEAT + j];
#pragma unroll
        for (int u = 0; u < 8; ++u) acc += (kk[u] > kth) ? vv[u] : 0.f;  // same seq FP order
    }
    for (; p < hi; ++p) {
        if (keys[p] > kth) acc += hs[(size_t)csr_src[p] * D_FEAT + j];
    }
    h_out[(size_t)g * D_FEAT + j] = acc * nrm[g];
}

// out = h @ W^T ; stage W transposed in LDS (pad 33, conflict-free)
__global__ void fc_kernel(const float* __restrict__ h, const float* __restrict__ W,
                          float* __restrict__ out, int N) {
    __shared__ float Wt[32][33];
    int t = threadIdx.x;
    for (int i = t; i < 1024; i += 256) Wt[i & 31][i >> 5] = W[i];
    __syncthreads();
    int node = blockIdx.x * 8 + (t >> 5);
    if (node >= N) return;
    int o = t & 31;
    const float* hr = h + (size_t)node * D_FEAT;
    float acc = 0.f;
#pragma unroll
    for (int j = 0; j < 32; ++j) acc += hr[j] * Wt[j][o];
    out[(size_t)node * D_FEAT + o] = acc;
}

extern "C" void kernel_launch(void* const* d_in, const int* in_sizes, int n_in,
                              void* d_out, int out_size, void* d_ws, size_t ws_size,
                              hipStream_t stream) {
    const float* features = (const float*)d_in[0];
    const float* W        = (const float*)d_in[1];
    const int*   src      = (const int*)d_in[2];
    const int*   dst      = (const int*)d_in[3];
    float*       out      = (float*)d_out;

    char* ws = (char*)d_ws;
    size_t o = 0;
    auto take = [&](size_t bytes) -> char* {
        char* p = ws + o;
        o += (bytes + 255) & ~(size_t)255;
        return p;
    };
    int*                deg     = (int*)take((size_t)N_NODES * 4);
    float*              nrm     = (float*)take((size_t)N_NODES * 4);
    int*                offs    = (int*)take((size_t)(N_NODES + 1) * 4);
    int*                bcur    = (int*)take((size_t)NBKT * 4);
    int*                csr_src = (int*)take((size_t)N_EDGES * 4);
    int*                csr_dst = (int*)take((size_t)N_EDGES * 4);
    int*                csr_eid = (int*)take((size_t)N_EDGES * 4);
    float*              hA      = (float*)take((size_t)N_NODES * D_FEAT * 4);
    float*              hB      = (float*)take((size_t)N_NODES * D_FEAT * 4);
    float*              nh      = (float*)take((size_t)N_NODES * D_FEAT * 4);
    float*              hs      = (float*)take((size_t)N_NODES * D_FEAT * 4);
    unsigned long long* keys    = (unsigned long long*)take((size_t)N_EDGES * 8);
    unsigned int*       ghist   = (unsigned int*)take((size_t)256 * 4);
    SelState*           st      = (SelState*)take(256);
    int*                bsum    = (int*)take((size_t)SCAN_NB * 4);
    int*                boff    = (int*)take((size_t)SCAN_NB * 4);
    int*                cnt_a   = (int*)take((size_t)HC_NB * 4);
    int*                cnt_b   = (int*)take((size_t)HC_NB * 4);

    // candidate slice buffers alias dead memory during the radix passes:
    // nh is dead after coskey; hB is written only by hop-2 aggregate (after selection).
    unsigned long long* candA = (unsigned long long*)nh;
    unsigned long long* candB = (unsigned long long*)hB;
    // keys is dead during CSR build -> binsort overflow scratch
    int* scratch = (int*)keys;

    hipMemsetAsync(deg, 0, (size_t)N_NODES * 4, stream);
    hipMemsetAsync(ghist, 0, (size_t)256 * 4, stream);

    deg_kernel<<<(N_EDGES + 255) / 256, 256, 0, stream>>>(dst, deg, N_EDGES);
    norm_kernel<<<(N_NODES + 255) / 256, 256, 0, stream>>>(deg, nrm, N_NODES);
    blocksum_kernel<<<SCAN_NB, 256, 0, stream>>>(deg, bsum, N_NODES);
    scanpartial_kernel<<<1, 512, 0, stream>>>(bsum, boff, SCAN_NB);
    writeoffs_kernel<<<SCAN_NB, 256, 0, stream>>>(deg, boff, offs, N_NODES);
    bcur_init_kernel<<<(NBKT + 255) / 256, 256, 0, stream>>>(offs, bcur, NBKT);
    fill_bkt_kernel<<<(N_EDGES + 255) / 256, 256, 0, stream>>>(dst, bcur, csr_eid, N_EDGES);
    binsort_kernel<<<NBKT, 256, 0, stream>>>(dst, offs, csr_eid, scratch, N_NODES);
    expand_kernel<<<(N_NODES + 7) / 8, 256, 0, stream>>>(src, offs, csr_eid,
                                                         csr_src, csr_dst, N_NODES);

    const float* hin = features;
    float* houts[2] = { hA, hB };
    for (int hop = 0; hop < 2; ++hop) {
        float* hout = houts[hop];
        rownorm_kernel<<<(N_NODES + 255) / 256, 256, 0, stream>>>(hin, nh, hs, nrm, st, N_NODES);
        coskey_kernel<<<COSKEY_NB, 256, 0, stream>>>(nh, csr_src, csr_dst, csr_eid,
                                                     keys, ghist, N_EDGES);
        scan8_kernel<<<1, 256, 0, stream>>>(ghist, st);   // digit 0
        for (int pass = 1; pass < 8; ++pass) {
            const unsigned long long* in =
                (pass == 1) ? keys : ((pass & 1) ? candB : candA);
            const int* cin = (pass == 1) ? (const int*)nullptr
                                         : ((pass & 1) ? cnt_b : cnt_a);
            unsigned long long* outc = (pass & 1) ? candA : candB;
            int* cout = (pass & 1) ? cnt_a : cnt_b;
            histc_kernel<<<HC_NB, 256, 0, stream>>>(in, cin, outc, cout, st, ghist, pass);
            scan8_kernel<<<1, 256, 0, stream>>>(ghist, st);
        }
        aggregate_csr_kernel<<<(N_NODES + 7) / 8, 256, 0, stream>>>(
            hs, hout, offs, csr_src, keys, st, nrm, N_NODES);
        hin = hout;
    }
    fc_kernel<<<(N_NODES + 7) / 8, 256, 0, stream>>>(hin, W, out, N_NODES);
}

// Round 12
// 738.851 us; speedup vs baseline: 1.1327x; 1.1327x over previous
//
#include <hip/hip_runtime.h>
#include <hip/hip_bf16.h>
#include <stdint.h>

#define N_NODES 100000
#define N_EDGES 1600000
#define D_FEAT 32
#define CUT_K 320000        // int(N_EDGES * 0.2)
#define COSKEY_NB 4096      // coskey grid: enough blocks for full occupancy
#define HC_NB 1000          // histc blocks; E = HC_NB * HC_SLICE exactly
#define HC_SLICE 1600
#define SCAN_NB ((N_NODES + 255) / 256)   // 391
#define X8_NB 4096          // XCD-partitioned scatter grid (512 blocks/class)
#define CLS_DIV 12500       // N_NODES / 8 -> dst partition per XCD class

// ---- selection-state derivation (replaces scan8 kernels + SelState) ----
// ghist layout: [hop*8 + pass][256] bins, zeroed once per call.
// Any block re-derives (prefix, k) after `npass` digits by replaying the
// digit-at-rank-k scans with a single wave (shuffle scan, no barriers).
__device__ __forceinline__ void derive_sel(const unsigned int* __restrict__ gh, int npass,
                                           unsigned long long* prefix_out,
                                           unsigned int* k_out) {
    int lane = threadIdx.x & 63;
    unsigned long long prefix = 0ull;
    unsigned int k = CUT_K;
    for (int q = 0; q < npass; ++q) {
        const unsigned int* h = gh + q * 256;
        unsigned int b0 = h[lane * 4], b1 = h[lane * 4 + 1];
        unsigned int b2 = h[lane * 4 + 2], b3 = h[lane * 4 + 3];
        unsigned int s = b0 + b1 + b2 + b3;
        unsigned int inc = s;
#pragma unroll
        for (int off = 1; off < 64; off <<= 1) {
            unsigned int v = __shfl_up(inc, off, 64);
            if (lane >= off) inc += v;
        }
        unsigned int excl = inc - s;
        unsigned long long m = __ballot(excl < k && k <= inc);
        int wl = __ffsll((unsigned long long)m) - 1;   // exactly one lane matches
        unsigned int wexcl = __shfl(excl, wl, 64);
        unsigned int w0 = __shfl(b0, wl, 64), w1 = __shfl(b1, wl, 64);
        unsigned int w2 = __shfl(b2, wl, 64), w3 = __shfl(b3, wl, 64);
        unsigned int run = wexcl;
        int dig = wl * 4;
        if (k <= run + w0) { }
        else if (k <= run + w0 + w1) { run += w0; dig += 1; }
        else if (k <= run + w0 + w1 + w2) { run += w0 + w1; dig += 2; }
        else { run += w0 + w1 + w2; dig += 3; }
        prefix = (prefix << 8) | (unsigned long long)dig;
        k -= run;
    }
    *prefix_out = prefix;
    *k_out = k;
}

// XCD-partitioned degree count: class c = blockIdx&7 handles dst range
// [c*12500,(c+1)*12500) so each deg line is written from one XCD only.
__global__ void deg_x8_kernel(const int* __restrict__ dst, int* __restrict__ deg, int E) {
    int cls = blockIdx.x & 7;
    int vb = blockIdx.x >> 3;
    int stride = (gridDim.x >> 3) * blockDim.x;
    for (int e = vb * blockDim.x + threadIdx.x; e < E; e += stride) {
        int d = dst[e];
        if (d / CLS_DIV == cls) atomicAdd(&deg[d], 1);
    }
}

__global__ void norm_kernel(const int* __restrict__ deg, float* __restrict__ nrm, int N) {
    int i = blockIdx.x * blockDim.x + threadIdx.x;
    if (i < N) nrm[i] = 1.0f / sqrtf(fmaxf((float)deg[i], 1.0f));
}

// ---- parallel exclusive scan of deg (3 kernels) ----
__global__ void blocksum_kernel(const int* __restrict__ deg, int* __restrict__ bsum, int N) {
    int i = blockIdx.x * 256 + threadIdx.x;
    int v = (i < N) ? deg[i] : 0;
#pragma unroll
    for (int off = 32; off > 0; off >>= 1) v += __shfl_down(v, off, 64);
    __shared__ int ws4[4];
    if ((threadIdx.x & 63) == 0) ws4[threadIdx.x >> 6] = v;
    __syncthreads();
    if (threadIdx.x == 0) bsum[blockIdx.x] = ws4[0] + ws4[1] + ws4[2] + ws4[3];
}

__global__ void scanpartial_kernel(const int* __restrict__ bsum, int* __restrict__ boff, int B) {
    __shared__ int buf[512];
    int t = threadIdx.x;
    int v = (t < B) ? bsum[t] : 0;
    buf[t] = v;
    __syncthreads();
    for (int off = 1; off < 512; off <<= 1) {
        int u = (t >= off) ? buf[t - off] : 0;
        __syncthreads();
        buf[t] += u;
        __syncthreads();
    }
    if (t < B) boff[t] = buf[t] - v;   // exclusive
}

__global__ void writeoffs_kernel(const int* __restrict__ deg, const int* __restrict__ boff,
                                 int* __restrict__ offs, int* __restrict__ cursor, int N) {
    __shared__ int buf[256];
    int t = threadIdx.x;
    int i = blockIdx.x * 256 + t;
    int v = (i < N) ? deg[i] : 0;
    buf[t] = v;
    __syncthreads();
    for (int off = 1; off < 256; off <<= 1) {
        int u = (t >= off) ? buf[t - off] : 0;
        __syncthreads();
        buf[t] += u;
        __syncthreads();
    }
    int ex = buf[t] - v + boff[blockIdx.x];
    if (i < N) { offs[i] = ex; cursor[i] = ex; }
    if (i == N - 1) offs[N] = ex + v;   // == E
}

// XCD-partitioned eid scatter: class c writes only csr_eid positions belonging
// to dst range c -> a contiguous ~1.6MB region owned by one XCD's L2, so each
// 64B line absorbs ~16 appends before a single writeback. (R11 showed that a
// hot-but-XCD-shared line never coalesces: 75MB writeback. Ownership fixes it.)
__global__ void fill_x8_kernel(const int* __restrict__ dst, int* __restrict__ cursor,
                               int* __restrict__ csr_eid, int E) {
    int cls = blockIdx.x & 7;
    int vb = blockIdx.x >> 3;
    int stride = (gridDim.x >> 3) * blockDim.x;
    for (int e = vb * blockDim.x + threadIdx.x; e < E; e += stride) {
        int d = dst[e];
        if (d / CLS_DIV == cls) {
            int pos = atomicAdd(&cursor[d], 1);
            csr_eid[pos] = e;
        }
    }
}

// canonicalize each segment: in-place insertion sort by eid (one thread per node).
// Keeps the whole pipeline bitwise deterministic across calls.
__global__ void sortseg_kernel(const int* __restrict__ offs, int* __restrict__ csr_eid, int N) {
    int g = blockIdx.x * blockDim.x + threadIdx.x;
    if (g >= N) return;
    int lo = offs[g], hi = offs[g + 1];
    for (int i = lo + 1; i < hi; ++i) {
        int key = csr_eid[i];
        int j = i - 1;
        while (j >= lo && csr_eid[j] > key) { csr_eid[j + 1] = csr_eid[j]; --j; }
        csr_eid[j + 1] = key;
    }
}

// once per call: materialize csr_src / csr_dst with coalesced writes.
__global__ void expand_kernel(const int* __restrict__ src, const int* __restrict__ offs,
                              const int* __restrict__ csr_eid,
                              int* __restrict__ csr_src, int* __restrict__ csr_dst, int N) {
    int g = blockIdx.x * 8 + (threadIdx.x >> 5);
    int j = threadIdx.x & 31;
    if (g >= N) return;
    int lo = offs[g], hi = offs[g + 1];
    for (int p = lo + j; p < hi; p += 32) {
        csr_dst[p] = g;
        csr_src[p] = src[csr_eid[p]];
    }
}

// nh = h / max(||h||,1e-12)  AND  hs = h * nrm  (fused)
__global__ void rownorm_kernel(const float* __restrict__ h, float* __restrict__ nh,
                               float* __restrict__ hs, const float* __restrict__ nrm, int N) {
    int i = blockIdx.x * blockDim.x + threadIdx.x;
    if (i >= N) return;
    const float4* hp = (const float4*)(h + (size_t)i * D_FEAT);
    float4 v[8];
    float ss = 0.f;
#pragma unroll
    for (int q = 0; q < 8; ++q) {
        v[q] = hp[q];
        ss += v[q].x * v[q].x + v[q].y * v[q].y + v[q].z * v[q].z + v[q].w * v[q].w;
    }
    float inv = 1.0f / fmaxf(sqrtf(ss), 1e-12f);
    float sc = nrm[i];
    float4* op = (float4*)(nh + (size_t)i * D_FEAT);
    float4* sp = (float4*)(hs + (size_t)i * D_FEAT);
#pragma unroll
    for (int q = 0; q < 8; ++q) {
        float4 ov = v[q];
        float4 sv = v[q];
        ov.x *= inv; ov.y *= inv; ov.z *= inv; ov.w *= inv;
        sv.x *= sc;  sv.y *= sc;  sv.z *= sc;  sv.w *= sc;
        op[q] = ov;
        sp[q] = sv;
    }
}

// keys[p] = (sortable(cos_p) << 32) | orig_eid; fused pass-0 histogram into gh0
__global__ void coskey_kernel(const float* __restrict__ nh, const int* __restrict__ csr_src,
                              const int* __restrict__ csr_dst, const int* __restrict__ csr_eid,
                              unsigned long long* __restrict__ keys,
                              unsigned int* __restrict__ gh0, int E) {
    __shared__ unsigned int lh[4][256];
    int t = threadIdx.x;
#pragma unroll
    for (int w = 0; w < 4; ++w) lh[w][t] = 0u;
    __syncthreads();
    int wave = t >> 6;
    int stride = gridDim.x * blockDim.x;
    for (int p = blockIdx.x * blockDim.x + t; p < E; p += stride) {
        const float4* a = (const float4*)(nh + (size_t)csr_src[p] * D_FEAT);
        const float4* b = (const float4*)(nh + (size_t)csr_dst[p] * D_FEAT);
        float s = 0.f;
#pragma unroll
        for (int q = 0; q < 8; ++q) {
            float4 x = a[q], y = b[q];
            s += x.x * y.x + x.y * y.y + x.z * y.z + x.w * y.w;
        }
        unsigned int u = __float_as_uint(s);
        unsigned int so = (u & 0x80000000u) ? ~u : (u | 0x80000000u);
        unsigned long long key = ((unsigned long long)so << 32) | (unsigned int)csr_eid[p];
        keys[p] = key;
        atomicAdd(&lh[wave][(unsigned int)(key >> 56)], 1u);
    }
    __syncthreads();
    unsigned int tot = lh[0][t] + lh[1][t] + lh[2][t] + lh[3][t];
    if (tot) atomicAdd(&gh0[t], tot);
}

// compacting radix pass p (1..7): derive prefix in-block (wave 0), filter,
// histogram next digit into gh_base[pass], compact survivors to private slice.
__global__ void histc_kernel(const unsigned long long* __restrict__ in,
                             const int* __restrict__ cnt_in,      // null => dense (pass 1)
                             unsigned long long* __restrict__ out,
                             int* __restrict__ cnt_out,
                             unsigned int* __restrict__ gh_base, int pass) {
    __shared__ unsigned int lh[4][256];
    __shared__ unsigned int lcnt;
    __shared__ unsigned long long s_prefix;
    int t = threadIdx.x, b = blockIdx.x;
#pragma unroll
    for (int w = 0; w < 4; ++w) lh[w][t] = 0u;
    if (t == 0) lcnt = 0u;
    if (t < 64) {
        unsigned long long pfx; unsigned int kk;
        derive_sel(gh_base, pass, &pfx, &kk);
        if (t == 0) s_prefix = pfx;
    }
    __syncthreads();
    unsigned long long prefix = s_prefix;
    int n = cnt_in ? cnt_in[b] : HC_SLICE;
    const unsigned long long* sin = in + (size_t)b * HC_SLICE;
    unsigned long long* sout = out + (size_t)b * HC_SLICE;
    int wave = t >> 6;
    int fshift = 64 - 8 * pass;
    int dshift = 56 - 8 * pass;
    for (int i = t; i < n; i += 256) {
        unsigned long long key = sin[i];
        if ((key >> fshift) == prefix) {
            atomicAdd(&lh[wave][(unsigned int)((key >> dshift) & 0xFFull)], 1u);
            unsigned int slot = atomicAdd(&lcnt, 1u);   // LDS atomic, block-local
            sout[slot] = key;
        }
    }
    __syncthreads();
    if (t == 0) cnt_out[b] = (int)lcnt;
    unsigned int tot = lh[0][t] + lh[1][t] + lh[2][t] + lh[3][t];
    if (tot) atomicAdd(&gh_base[pass * 256 + t], tot);
}

// pull aggregation: derive kth in-block, then one 32-lane group per node walks
// its (eid-sorted) CSR segment; 8x unrolled unconditional gathers for MLP.
__global__ void aggregate_csr_kernel(const float* __restrict__ hs, float* __restrict__ h_out,
                                     const int* __restrict__ offs, const int* __restrict__ csr_src,
                                     const unsigned long long* __restrict__ keys,
                                     const unsigned int* __restrict__ gh_base,
                                     const float* __restrict__ nrm, int N) {
    __shared__ unsigned long long s_kth;
    if (threadIdx.x < 64) {
        unsigned long long pfx; unsigned int kk;
        derive_sel(gh_base, 8, &pfx, &kk);
        if (threadIdx.x == 0) s_kth = pfx;
    }
    __syncthreads();
    unsigned long long kth = s_kth;        // cut_k-th smallest composite key
    int g = blockIdx.x * 8 + (threadIdx.x >> 5);
    int j = threadIdx.x & 31;
    if (g >= N) return;
    int lo = offs[g], hi = offs[g + 1];
    float acc = 0.f;
    int p = lo;
    for (; p + 8 <= hi; p += 8) {
        unsigned long long kk[8];
        int ss[8];
#pragma unroll
        for (int u = 0; u < 8; ++u) { kk[u] = keys[p + u]; ss[u] = csr_src[p + u]; }
        float vv[8];
#pragma unroll
        for (int u = 0; u < 8; ++u) vv[u] = hs[(size_t)ss[u] * D_FEAT + j];
#pragma unroll
        for (int u = 0; u < 8; ++u) acc += (kk[u] > kth) ? vv[u] : 0.f;  // same seq FP order
    }
    for (; p < hi; ++p) {
        if (keys[p] > kth) acc += hs[(size_t)csr_src[p] * D_FEAT + j];
    }
    h_out[(size_t)g * D_FEAT + j] = acc * nrm[g];
}

// out = h @ W^T ; stage W transposed in LDS (pad 33, conflict-free)
__global__ void fc_kernel(const float* __restrict__ h, const float* __restrict__ W,
                          float* __restrict__ out, int N) {
    __shared__ float Wt[32][33];
    int t = threadIdx.x;
    for (int i = t; i < 1024; i += 256) Wt[i & 31][i >> 5] = W[i];
    __syncthreads();
    int node = blockIdx.x * 8 + (t >> 5);
    if (node >= N) return;
    int o = t & 31;
    const float* hr = h + (size_t)node * D_FEAT;
    float acc = 0.f;
#pragma unroll
    for (int j = 0; j < 32; ++j) acc += hr[j] * Wt[j][o];
    out[(size_t)node * D_FEAT + o] = acc;
}

extern "C" void kernel_launch(void* const* d_in, const int* in_sizes, int n_in,
                              void* d_out, int out_size, void* d_ws, size_t ws_size,
                              hipStream_t stream) {
    const float* features = (const float*)d_in[0];
    const float* W        = (const float*)d_in[1];
    const int*   src      = (const int*)d_in[2];
    const int*   dst      = (const int*)d_in[3];
    float*       out      = (float*)d_out;

    char* ws = (char*)d_ws;
    size_t o = 0;
    auto take = [&](size_t bytes) -> char* {
        char* p = ws + o;
        o += (bytes + 255) & ~(size_t)255;
        return p;
    };
    int*                deg     = (int*)take((size_t)N_NODES * 4);
    float*              nrm     = (float*)take((size_t)N_NODES * 4);
    int*                offs    = (int*)take((size_t)(N_NODES + 1) * 4);
    int*                cursor  = (int*)take((size_t)N_NODES * 4);
    int*                csr_src = (int*)take((size_t)N_EDGES * 4);
    int*                csr_dst = (int*)take((size_t)N_EDGES * 4);
    int*                csr_eid = (int*)take((size_t)N_EDGES * 4);
    float*              hA      = (float*)take((size_t)N_NODES * D_FEAT * 4);
    float*              hB      = (float*)take((size_t)N_NODES * D_FEAT * 4);
    float*              nh      = (float*)take((size_t)N_NODES * D_FEAT * 4);
    float*              hs      = (float*)take((size_t)N_NODES * D_FEAT * 4);
    unsigned long long* keys    = (unsigned long long*)take((size_t)N_EDGES * 8);
    unsigned int*       ghist   = (unsigned int*)take((size_t)2 * 8 * 256 * 4);
    int*                bsum    = (int*)take((size_t)SCAN_NB * 4);
    int*                boff    = (int*)take((size_t)SCAN_NB * 4);
    int*                cnt_a   = (int*)take((size_t)HC_NB * 4);
    int*                cnt_b   = (int*)take((size_t)HC_NB * 4);

    // candidate slice buffers alias dead memory during the radix passes:
    // nh is dead after coskey; hB is written only by hop-2 aggregate (after selection).
    unsigned long long* candA = (unsigned long long*)nh;
    unsigned long long* candB = (unsigned long long*)hB;

    hipMemsetAsync(deg, 0, (size_t)N_NODES * 4, stream);
    hipMemsetAsync(ghist, 0, (size_t)2 * 8 * 256 * 4, stream);

    deg_x8_kernel<<<X8_NB, 256, 0, stream>>>(dst, deg, N_EDGES);
    norm_kernel<<<(N_NODES + 255) / 256, 256, 0, stream>>>(deg, nrm, N_NODES);
    blocksum_kernel<<<SCAN_NB, 256, 0, stream>>>(deg, bsum, N_NODES);
    scanpartial_kernel<<<1, 512, 0, stream>>>(bsum, boff, SCAN_NB);
    writeoffs_kernel<<<SCAN_NB, 256, 0, stream>>>(deg, boff, offs, cursor, N_NODES);
    fill_x8_kernel<<<X8_NB, 256, 0, stream>>>(dst, cursor, csr_eid, N_EDGES);
    sortseg_kernel<<<SCAN_NB, 256, 0, stream>>>(offs, csr_eid, N_NODES);
    expand_kernel<<<(N_NODES + 7) / 8, 256, 0, stream>>>(src, offs, csr_eid,
                                                         csr_src, csr_dst, N_NODES);

    const float* hin = features;
    float* houts[2] = { hA, hB };
    for (int hop = 0; hop < 2; ++hop) {
        float* hout = houts[hop];
        unsigned int* gh_base = ghist + (size_t)hop * 8 * 256;
        rownorm_kernel<<<(N_NODES + 255) / 256, 256, 0, stream>>>(hin, nh, hs, nrm, N_NODES);
        coskey_kernel<<<COSKEY_NB, 256, 0, stream>>>(nh, csr_src, csr_dst, csr_eid,
                                                     keys, gh_base, N_EDGES);
        for (int pass = 1; pass < 8; ++pass) {
            const unsigned long long* in =
                (pass == 1) ? keys : ((pass & 1) ? candB : candA);
            const int* cin = (pass == 1) ? (const int*)nullptr
                                         : ((pass & 1) ? cnt_b : cnt_a);
            unsigned long long* outc = (pass & 1) ? candA : candB;
            int* cout = (pass & 1) ? cnt_a : cnt_b;
            histc_kernel<<<HC_NB, 256, 0, stream>>>(in, cin, outc, cout, gh_base, pass);
        }
        aggregate_csr_kernel<<<(N_NODES + 7) / 8, 256, 0, stream>>>(
            hs, hout, offs, csr_src, keys, gh_base, nrm, N_NODES);
        hin = hout;
    }
    fc_kernel<<<(N_NODES + 7) / 8, 256, 0, stream>>>(hin, W, out, N_NODES);
}